// Round 11
// baseline (477.041 us; speedup 1.0000x reference)
//
#include <hip/hip_runtime.h>
#include <hip/hip_bf16.h>

// Grouped experts GEMM: out[t, o] = sum_k input[t,k] * weight[e(t), o, k] + bias[e(t), o]
// E=8, T=32768, DIN(K)=1024, DOUT(N)=4096.
//
// Round 11: round-8 kernel (best: GEMM 311 us) with the MFMA shape switched
// 16x16x32 -> 32x32x16 (m119: 2382 vs 2075 TF ceiling, 17% fewer matrix-pipe
// cycles/FLOP; half the MFMA instruction count -> half the issue pressure).
// LDS layout, staging, swizzle, persistent walk, 3-barrier K-tile skeleton,
// vmcnt accounting all identical to round 8. Reads stay 24 b128/wave/K-tile.

#define DEVFN __device__ __forceinline__

constexpr int E_    = 8;
constexpr int T_    = 32768;
constexpr int DIN_  = 1024;   // K
constexpr int DOUT_ = 4096;   // N

typedef __attribute__((ext_vector_type(8)))  __bf16 bf16x8;   // MFMA A/B frag (4 VGPR)
typedef __attribute__((ext_vector_type(4)))  float  f32x4;
typedef __attribute__((ext_vector_type(16))) float  f32x16;   // 32x32 C/D frag
typedef __attribute__((ext_vector_type(8)))  short  s16x8;

DEVFN unsigned short f2bf(float x) {
  unsigned u = __builtin_bit_cast(unsigned, x);
  u += 0x7fffu + ((u >> 16) & 1u);
  return (unsigned short)(u >> 16);
}

DEVFN long long expert_offset(const void* cnts, int e) {
  const int* c32 = (const int*)cnts;
  long long s = 0;
  for (int i = 0; i < E_; ++i) s += c32[i];
  if (s == (long long)T_) {
    long long o = 0;
    for (int i = 0; i < e; ++i) o += c32[i];
    return o;
  }
  const long long* c64 = (const long long*)cnts;
  long long o = 0;
  for (int i = 0; i < e; ++i) o += c64[i];
  return o;
}

// Combined f32->bf16 conversion for input (nA4 float4s) and weight (nW4).
__global__ __launch_bounds__(256) void cvt2_kernel(const float* __restrict__ ia,
                                                   const float* __restrict__ iw,
                                                   unsigned short* __restrict__ oa,
                                                   unsigned short* __restrict__ ow,
                                                   int nA4, int nW4) {
  int i = blockIdx.x * 256 + threadIdx.x;
  const float* src;
  unsigned short* dst;
  int j;
  if (i < nA4) { src = ia; dst = oa; j = i; }
  else         { j = i - nA4; if (j >= nW4) return; src = iw; dst = ow; }
  const float4 f = reinterpret_cast<const float4*>(src)[j];
  ushort4 h;
  h.x = f2bf(f.x); h.y = f2bf(f.y); h.z = f2bf(f.z); h.w = f2bf(f.w);
  reinterpret_cast<ushort4*>(dst)[j] = h;
}

// ---------------------------------------------------------------------------
// Persistent grouped GEMM: 256 blocks x 512 threads; block p -> expert e=p&7
// (XCD-local), q=p>>3 in [0,32). 8 tiles per block:
//   tm = (it&3)*4 + (q>>3), tn = (it>>2)*8 + (q&7)
// Per tile: 256x256, 8 waves (2Mx4N), per-wave 128x64 via 32x32x16 MFMA:
// 4 m-frags x 2 n-frags, acc[4][2] f32x16. BK=64 (4 K-steps of 16).
// LDS: 2 buffers x (A 32KB + B 32KB) = 128 KiB; granule swizzle g^=(row&7)
// on pre-swizzled global source + ds_read address (involution, r8-proven).
// A/B lane layout (32x32x16): row = lane&31, k = (lane>>5)*8 + j ->
// granule (2s + (lane>>5)) ^ (row&7). C/D: col=lane&31,
// row=(reg&3)+8*(reg>>2)+4*(lane>>5)  [m74/m101-verified].
// K-tile schedule (3 barriers, r8 skeleton):
//   reads A-mf01 + B-nf0 ; 8 MFMA ; reads B-nf1 ; 8 MFMA ; BARRIER
//   stage B(kt+2) ; reads A-mf23 ; 8 MFMA ; BARRIER
//   stage A(kt+2) ; 8 MFMA ; vmcnt(8) ; BARRIER
// kt14/15 stage next tile's kt0/1 -> one seamless 128-K-tile pipeline.
// ---------------------------------------------------------------------------
__global__ __launch_bounds__(512, 2) void gemm11_kernel(const unsigned short* __restrict__ wa,
                                                        const unsigned short* __restrict__ wb,
                                                        const float* __restrict__ bias,
                                                        const void* __restrict__ counts,
                                                        float* __restrict__ out) {
  __shared__ __align__(16) unsigned char lds[2][2][32768];

  const int tid  = threadIdx.x;
  const int lane = tid & 63;
  const int wid  = tid >> 6;
  const int wm = wid >> 2, wn = wid & 3;   // 2 x 4 wave grid

  const int p = blockIdx.x;
  const int e = p & 7;
  const int q = p >> 3;                    // 0..31

  const long long off = expert_offset(counts, e);
  const unsigned short* wae = wa + off * (long long)DIN_;
  const unsigned short* wbe = wb + (long long)e * DOUT_ * DIN_;
  const float* be = bias + e * DOUT_;

  int goff[4];
#pragma unroll
  for (int rd = 0; rd < 4; ++rd) {
    const int chunk = rd * 512 + tid;
    const int r = chunk >> 3, c = chunk & 7;
    goff[rd] = r * DIN_ + ((c ^ (r & 7)) << 3);   // pre-swizzled global element offset
  }
  auto stage = [&](const unsigned short* g, unsigned char* l) {
#pragma unroll
    for (int rd = 0; rd < 4; ++rd)
      __builtin_amdgcn_global_load_lds(
          (const __attribute__((address_space(1))) void*)(g + goff[rd]),
          (__attribute__((address_space(3))) void*)(l + (rd * 512 + tid) * 16), 16, 0, 0);
  };

  // 32x32 fragment addressing: row = base + r32, k-granule = (2s+h2)^(row&7).
  const int r32 = lane & 31, h2 = lane >> 5;
  int gsw[4];                         // swizzled granule byte offset per K-step
#pragma unroll
  for (int s = 0; s < 4; ++s) gsw[s] = (((2 * s + h2) ^ (r32 & 7)) << 4);
  int arow[4], brow[2];               // row-base byte offsets
#pragma unroll
  for (int mf = 0; mf < 4; ++mf) arow[mf] = (wm * 128 + mf * 32 + r32) * 128;
#pragma unroll
  for (int nf = 0; nf < 2; ++nf) brow[nf] = (wn * 64 + nf * 32 + r32) * 128;

  bf16x8 a01[2][4], a23[2][4];   // A frags [mf][s]
  bf16x8 b0[4], b1[4];           // B frags [s]
  f32x16 acc[4][2];              // [mf][nf]

  // Tile 0 pointers + prologue staging (K-tiles 0,1 of tile 0).
  int tm = q >> 3, tn = q & 7;
  const unsigned short* wat = wae + (long long)tm * 256 * DIN_;
  const unsigned short* wbt = wbe + (long long)tn * 256 * DIN_;
  stage(wat,      &lds[0][0][0]);
  stage(wbt,      &lds[0][1][0]);
  stage(wat + 64, &lds[1][0][0]);
  stage(wbt + 64, &lds[1][1][0]);
  asm volatile("s_waitcnt vmcnt(8)" ::: "memory");   // K-tile 0 landed; 1 in flight
  __builtin_amdgcn_s_barrier();

  for (int it = 0; it < 8; ++it) {
    const int ocol0 = tn * 256 + wn * 64;
    // Bias folded into accumulator init (epilogue becomes pure stores).
    {
      const float bv0 = be[ocol0 + r32];
      const float bv1 = be[ocol0 + 32 + r32];
#pragma unroll
      for (int mf = 0; mf < 4; ++mf) {
#pragma unroll
        for (int j = 0; j < 16; ++j) { acc[mf][0][j] = bv0; acc[mf][1][j] = bv1; }
      }
    }
    const bool have_next = (it < 7);
    int ntm = tm, ntn = tn;
    if (have_next) { ntm = ((it + 1) & 3) * 4 + (q >> 3); ntn = ((it + 1) >> 2) * 8 + (q & 7); }
    const unsigned short* nat = wae + (long long)ntm * 256 * DIN_;
    const unsigned short* nbt = wbe + (long long)ntn * 256 * DIN_;

    for (int kt = 0; kt < 16; ++kt) {
      unsigned char* Ab = &lds[kt & 1][0][0];
      unsigned char* Bb = &lds[kt & 1][1][0];
      const unsigned short* pfa = nullptr;
      const unsigned short* pfb = nullptr;
      int nend = -1;
      if (kt < 14)        { pfa = wat + (kt + 2) * 64; pfb = wbt + (kt + 2) * 64; nend = 8; }
      else if (have_next) { pfa = nat + (kt - 14) * 64; pfb = nbt + (kt - 14) * 64; nend = 8; }
      else if (kt == 14)  { nend = 0; }

      // --- reads A-mf01 + B-nf0; MFMA (mf01 x nf0)
#pragma unroll
      for (int mf = 0; mf < 2; ++mf)
#pragma unroll
        for (int s = 0; s < 4; ++s)
          a01[mf][s] = *(const bf16x8*)(Ab + arow[mf] + gsw[s]);
#pragma unroll
      for (int s = 0; s < 4; ++s)
        b0[s] = *(const bf16x8*)(Bb + brow[0] + gsw[s]);
      __builtin_amdgcn_s_setprio(1);
#pragma unroll
      for (int mf = 0; mf < 2; ++mf)
#pragma unroll
        for (int s = 0; s < 4; ++s)
          acc[mf][0] = __builtin_amdgcn_mfma_f32_32x32x16_bf16(a01[mf][s], b0[s], acc[mf][0], 0, 0, 0);
      __builtin_amdgcn_s_setprio(0);
      // --- reads B-nf1; MFMA (mf01 x nf1)
#pragma unroll
      for (int s = 0; s < 4; ++s)
        b1[s] = *(const bf16x8*)(Bb + brow[1] + gsw[s]);
      __builtin_amdgcn_s_setprio(1);
#pragma unroll
      for (int mf = 0; mf < 2; ++mf)
#pragma unroll
        for (int s = 0; s < 4; ++s)
          acc[mf][1] = __builtin_amdgcn_mfma_f32_32x32x16_bf16(a01[mf][s], b1[s], acc[mf][1], 0, 0, 0);
      __builtin_amdgcn_s_setprio(0);
      __builtin_amdgcn_s_barrier();            // all waves' B reads complete
      if (pfb) stage(pfb, Bb);                 // overwrite B region (safe)
      // --- reads A-mf23; MFMA (mf23 x nf1)
#pragma unroll
      for (int mf = 0; mf < 2; ++mf)
#pragma unroll
        for (int s = 0; s < 4; ++s)
          a23[mf][s] = *(const bf16x8*)(Ab + arow[2 + mf] + gsw[s]);
      __builtin_amdgcn_s_setprio(1);
#pragma unroll
      for (int mf = 0; mf < 2; ++mf)
#pragma unroll
        for (int s = 0; s < 4; ++s)
          acc[2 + mf][1] = __builtin_amdgcn_mfma_f32_32x32x16_bf16(a23[mf][s], b1[s], acc[2 + mf][1], 0, 0, 0);
      __builtin_amdgcn_s_setprio(0);
      __builtin_amdgcn_s_barrier();            // all waves' A reads complete
      if (pfa) stage(pfa, Ab);                 // overwrite A region (safe)
      __builtin_amdgcn_sched_barrier(0);       // staging issues before MFMA cluster
      __builtin_amdgcn_s_setprio(1);
#pragma unroll
      for (int mf = 0; mf < 2; ++mf)
#pragma unroll
        for (int s = 0; s < 4; ++s)
          acc[2 + mf][0] = __builtin_amdgcn_mfma_f32_32x32x16_bf16(a23[mf][s], b0[s], acc[2 + mf][0], 0, 0, 0);
      __builtin_amdgcn_s_setprio(0);
      if (nend == 8)      asm volatile("s_waitcnt vmcnt(8)" ::: "memory");
      else if (nend == 0) asm volatile("s_waitcnt vmcnt(0)" ::: "memory");
      __builtin_amdgcn_s_barrier();
    }

    // Epilogue: pure stores (bias already in acc). 32x32 C/D: col=lane&31,
    // row=(reg&3)+8*(reg>>2)+4*h2. nf strided -> 2 x 128B segments per row.
    const long long orow0 = off + (long long)tm * 256 + wm * 128;
#pragma unroll
    for (int mf = 0; mf < 4; ++mf) {
#pragma unroll
      for (int j = 0; j < 16; ++j) {
        const int rl = mf * 32 + (j & 3) + 8 * (j >> 2) + 4 * h2;
        float* rp = out + (orow0 + rl) * (long long)DOUT_ + ocol0 + r32;
        rp[0]  = acc[mf][0][j];
        rp[32] = acc[mf][1][j];
      }
    }
    wat = nat; wbt = nbt; tm = ntm; tn = ntn;
  }
}

// ---------------------------------------------------------------------------
// Fallback (ws too small): 128x128, reg-staged f32->bf16 (round-1 proven).
// ---------------------------------------------------------------------------
__global__ __launch_bounds__(256) void gemm_fb_kernel(const float* __restrict__ Af,
                                                      const float* __restrict__ Bf,
                                                      const float* __restrict__ bias,
                                                      const void* __restrict__ counts,
                                                      float* __restrict__ out) {
  constexpr int RS = 144;
  constexpr int BBASE = 128 * RS;
  __shared__ __align__(16) unsigned char lds[2 * 128 * RS];

  const int tid  = threadIdx.x;
  const int lane = tid & 63;
  const int wid  = tid >> 6;
  const int wm = wid >> 1, wn = wid & 1;

  const int bid = blockIdx.x;
  const int e  = bid >> 10;
  const int t  = bid & 1023;
  const int tm = t >> 5, tn = t & 31;

  const long long off = expert_offset(counts, e);
  const long long rowA0 = off + (long long)tm * 128;
  const int n0 = tn * 128;

  f32x4 acc[4][4] = {};

  for (int kt = 0; kt < DIN_ / 64; ++kt) {
    const int k0 = kt * 64;
#pragma unroll
    for (int rd = 0; rd < 8; ++rd) {
      const int chunk = rd * 256 + tid;
      const int c2 = chunk & 1023;
      const int r  = c2 >> 3;
      const int c  = c2 & 7;
      const float* src =
          (rd < 4) ? (Af + (rowA0 + r) * (long long)DIN_ + (k0 + c * 8))
                   : (Bf + ((long long)(e * DOUT_ + n0 + r)) * DIN_ + (k0 + c * 8));
      const float4 f0 = *reinterpret_cast<const float4*>(src);
      const float4 f1 = *reinterpret_cast<const float4*>(src + 4);
      s16x8 v;
      v[0] = (short)f2bf(f0.x); v[1] = (short)f2bf(f0.y);
      v[2] = (short)f2bf(f0.z); v[3] = (short)f2bf(f0.w);
      v[4] = (short)f2bf(f1.x); v[5] = (short)f2bf(f1.y);
      v[6] = (short)f2bf(f1.z); v[7] = (short)f2bf(f1.w);
      *reinterpret_cast<s16x8*>(&lds[((rd < 4) ? 0 : BBASE) + r * RS + (c << 4)]) = v;
    }
    __syncthreads();
#pragma unroll
    for (int kk = 0; kk < 2; ++kk) {
      const int rs = lane & 15;
      const int cs = kk * 4 + (lane >> 4);
      bf16x8 af[4], bfr[4];
#pragma unroll
      for (int mf = 0; mf < 4; ++mf)
        af[mf] = *reinterpret_cast<const bf16x8*>(&lds[(wm * 64 + mf * 16 + rs) * RS + (cs << 4)]);
#pragma unroll
      for (int nf = 0; nf < 4; ++nf)
        bfr[nf] = *reinterpret_cast<const bf16x8*>(&lds[BBASE + (wn * 64 + nf * 16 + rs) * RS + (cs << 4)]);
#pragma unroll
      for (int mf = 0; mf < 4; ++mf)
#pragma unroll
        for (int nf = 0; nf < 4; ++nf)
          acc[mf][nf] = __builtin_amdgcn_mfma_f32_16x16x32_bf16(af[mf], bfr[nf], acc[mf][nf], 0, 0, 0);
    }
    __syncthreads();
  }

  const long long orow0 = off + (long long)tm * 128 + wm * 64;
  const int ocol0 = n0 + wn * 64;
  const int rlo = (lane >> 4) * 4;
  const int c15 = lane & 15;
#pragma unroll
  for (int nf = 0; nf < 4; ++nf) {
    const int n = ocol0 + nf * 16 + c15;
    const float bv = bias[e * DOUT_ + n];
#pragma unroll
    for (int mf = 0; mf < 4; ++mf) {
      const long long mrow = orow0 + mf * 16 + rlo;
#pragma unroll
      for (int j = 0; j < 4; ++j)
        out[(mrow + j) * (long long)DOUT_ + n] = acc[mf][nf][j] + bv;
    }
  }
}

extern "C" void kernel_launch(void* const* d_in, const int* in_sizes, int n_in,
                              void* d_out, int out_size, void* d_ws, size_t ws_size,
                              hipStream_t stream) {
  const float* input  = (const float*)d_in[0];
  const float* weight = (const float*)d_in[1];
  const float* bias   = (const float*)d_in[2];
  const void*  counts = (const void*)d_in[3];
  float* out = (float*)d_out;

  const size_t nA = (size_t)T_ * DIN_;
  const size_t nW = (size_t)E_ * DOUT_ * DIN_;
  const size_t need = (nA + nW) * sizeof(unsigned short);

  if (ws_size >= need) {
    unsigned short* wa = (unsigned short*)d_ws;
    unsigned short* wb = wa + nA;
    const int nA4 = (int)(nA / 4), nW4 = (int)(nW / 4);
    cvt2_kernel<<<dim3((unsigned)((nA4 + nW4) / 256)), dim3(256), 0, stream>>>(
        input, weight, wa, wb, nA4, nW4);
    gemm11_kernel<<<dim3(256), dim3(512), 0, stream>>>(wa, wb, bias, counts, out);
  } else {
    gemm_fb_kernel<<<dim3(E_ * 32 * 32), dim3(256), 0, stream>>>(input, weight, bias, counts, out);
  }
}

// Round 12
// 362.773 us; speedup vs baseline: 1.3150x; 1.3150x over previous
//
#include <hip/hip_runtime.h>
#include <hip/hip_bf16.h>

// Grouped experts GEMM: out[t, o] = sum_k input[t,k] * weight[e(t), o, k] + bias[e(t), o]
// E=8, T=32768, DIN(K)=1024, DOUT(N)=4096.
//
// Round 12: FINAL — revert to the round-8 kernel (best measured: GEMM
// 310-316 us, ~886 TF, total ~365 us). Falsified alternatives: 2-barrier
// merge (r5), B-direct-from-global (r6, L2-BW-bound), carried quadrant (r7),
// occupancy-first BK=32 (r9/r10, LDS-traffic-bound even at 0 conflicts),
// 32x32x16 shape (r11, structurally unavoidable 4-way LDS conflicts at
// 128B rows). r8 exceeds the documented grouped-GEMM reference for this
// regime (m248: 848 TF @ 256^2, K=1024).

#define DEVFN __device__ __forceinline__

constexpr int E_    = 8;
constexpr int T_    = 32768;
constexpr int DIN_  = 1024;   // K
constexpr int DOUT_ = 4096;   // N

typedef __attribute__((ext_vector_type(8))) __bf16 bf16x8;   // MFMA A/B frag (4 VGPR)
typedef __attribute__((ext_vector_type(4))) float  f32x4;    // MFMA C/D frag
typedef __attribute__((ext_vector_type(8))) short  s16x8;

DEVFN unsigned short f2bf(float x) {
  unsigned u = __builtin_bit_cast(unsigned, x);
  u += 0x7fffu + ((u >> 16) & 1u);
  return (unsigned short)(u >> 16);
}

DEVFN long long expert_offset(const void* cnts, int e) {
  const int* c32 = (const int*)cnts;
  long long s = 0;
  for (int i = 0; i < E_; ++i) s += c32[i];
  if (s == (long long)T_) {
    long long o = 0;
    for (int i = 0; i < e; ++i) o += c32[i];
    return o;
  }
  const long long* c64 = (const long long*)cnts;
  long long o = 0;
  for (int i = 0; i < e; ++i) o += c64[i];
  return o;
}

// Combined f32->bf16 conversion for input (nA4 float4s) and weight (nW4).
__global__ __launch_bounds__(256) void cvt2_kernel(const float* __restrict__ ia,
                                                   const float* __restrict__ iw,
                                                   unsigned short* __restrict__ oa,
                                                   unsigned short* __restrict__ ow,
                                                   int nA4, int nW4) {
  int i = blockIdx.x * 256 + threadIdx.x;
  const float* src;
  unsigned short* dst;
  int j;
  if (i < nA4) { src = ia; dst = oa; j = i; }
  else         { j = i - nA4; if (j >= nW4) return; src = iw; dst = ow; }
  const float4 f = reinterpret_cast<const float4*>(src)[j];
  ushort4 h;
  h.x = f2bf(f.x); h.y = f2bf(f.y); h.z = f2bf(f.z); h.w = f2bf(f.w);
  reinterpret_cast<ushort4*>(dst)[j] = h;
}

// ---------------------------------------------------------------------------
// Persistent grouped GEMM: 256 blocks x 512 threads; block p -> expert e=p&7
// (XCD-local), q=p>>3 in [0,32). 8 tiles per block:
//   tm = (it&3)*4 + (q>>3), tn = (it>>2)*8 + (q&7)
// Per tile: 256x256, 8 waves (2Mx4N), per-wave 128x64 = acc[8][4]. BK=64.
// LDS: 2 buffers x (A 32KB + B 32KB) = 128 KiB; granule swizzle c^=(r&7)
// applied on pre-swizzled global source + ds_read address (involution).
// K-tile schedule (3 barriers):
//   reads A-mq0, B-nq0 ; MFMA(0,0) ; reads B-nq1 ; MFMA(0,1) ; BARRIER
//   stage B(kt+2) ; reads A-mq1 ; MFMA(4,1) ; BARRIER
//   stage A(kt+2) ; MFMA(4,0) ; vmcnt(8) ; BARRIER
// kt14/15 stage next tile's kt0/1 -> one seamless 128-K-tile pipeline.
// ---------------------------------------------------------------------------
__global__ __launch_bounds__(512, 2) void gemm4_kernel(const unsigned short* __restrict__ wa,
                                                       const unsigned short* __restrict__ wb,
                                                       const float* __restrict__ bias,
                                                       const void* __restrict__ counts,
                                                       float* __restrict__ out) {
  __shared__ __align__(16) unsigned char lds[2][2][32768];

  const int tid  = threadIdx.x;
  const int lane = tid & 63;
  const int wid  = tid >> 6;
  const int wm = wid >> 2, wn = wid & 3;   // 2 x 4 wave grid

  const int p = blockIdx.x;
  const int e = p & 7;
  const int q = p >> 3;                    // 0..31

  const long long off = expert_offset(counts, e);
  const unsigned short* wae = wa + off * (long long)DIN_;
  const unsigned short* wbe = wb + (long long)e * DOUT_ * DIN_;
  const float* be = bias + e * DOUT_;

  int goff[4];
#pragma unroll
  for (int rd = 0; rd < 4; ++rd) {
    const int chunk = rd * 512 + tid;
    const int r = chunk >> 3, c = chunk & 7;
    goff[rd] = r * DIN_ + ((c ^ (r & 7)) << 3);   // pre-swizzled global element offset
  }
  auto stage = [&](const unsigned short* g, unsigned char* l) {
#pragma unroll
    for (int rd = 0; rd < 4; ++rd)
      __builtin_amdgcn_global_load_lds(
          (const __attribute__((address_space(1))) void*)(g + goff[rd]),
          (__attribute__((address_space(3))) void*)(l + (rd * 512 + tid) * 16), 16, 0, 0);
  };

  const int rsel = lane & 15, hi = lane >> 4;
  int lp[2];
  lp[0] = rsel * 128 + (((hi)     ^ (rsel & 7)) << 4);
  lp[1] = rsel * 128 + (((4 + hi) ^ (rsel & 7)) << 4);
  const int abase = wm * 128 * 128;  // wave's A-row block byte offset
  const int bbase = wn * 64 * 128;   // wave's B-row block byte offset

  bf16x8 a[4][2];        // A frags for current mq
  bf16x8 b[2][2][2];     // B frags [nq][j][kk]
  f32x4  acc[8][4];      // [mq*4+mf][nf]

  auto quad = [&](int am0, int qn) {
#pragma unroll
    for (int mf = 0; mf < 4; ++mf)
#pragma unroll
      for (int j = 0; j < 2; ++j)
#pragma unroll
        for (int kk = 0; kk < 2; ++kk)
          acc[am0 + mf][qn * 2 + j] = __builtin_amdgcn_mfma_f32_16x16x32_bf16(
              a[mf][kk], b[qn][j][kk], acc[am0 + mf][qn * 2 + j], 0, 0, 0);
  };

  // Tile 0 pointers + prologue staging (K-tiles 0,1 of tile 0).
  int tm = q >> 3, tn = q & 7;
  const unsigned short* wat = wae + (long long)tm * 256 * DIN_;
  const unsigned short* wbt = wbe + (long long)tn * 256 * DIN_;
  stage(wat,      &lds[0][0][0]);
  stage(wbt,      &lds[0][1][0]);
  stage(wat + 64, &lds[1][0][0]);
  stage(wbt + 64, &lds[1][1][0]);
  asm volatile("s_waitcnt vmcnt(8)" ::: "memory");   // K-tile 0 landed; 1 in flight
  __builtin_amdgcn_s_barrier();

  for (int it = 0; it < 8; ++it) {
    const int ocol0 = tn * 256 + wn * 64;
    // Bias folded into accumulator init (epilogue becomes pure stores).
    {
      const float bv0 = be[ocol0 + rsel];
      const float bv1 = be[ocol0 + 16 + rsel];
      const float bv2 = be[ocol0 + 32 + rsel];
      const float bv3 = be[ocol0 + 48 + rsel];
#pragma unroll
      for (int am = 0; am < 8; ++am) {
        acc[am][0] = (f32x4){bv0, bv0, bv0, bv0};
        acc[am][1] = (f32x4){bv1, bv1, bv1, bv1};
        acc[am][2] = (f32x4){bv2, bv2, bv2, bv2};
        acc[am][3] = (f32x4){bv3, bv3, bv3, bv3};
      }
    }
    const bool have_next = (it < 7);
    int ntm = tm, ntn = tn;
    if (have_next) { ntm = ((it + 1) & 3) * 4 + (q >> 3); ntn = ((it + 1) >> 2) * 8 + (q & 7); }
    const unsigned short* nat = wae + (long long)ntm * 256 * DIN_;
    const unsigned short* nbt = wbe + (long long)ntn * 256 * DIN_;

    for (int kt = 0; kt < 16; ++kt) {
      unsigned char* Ab = &lds[kt & 1][0][0];
      unsigned char* Bb = &lds[kt & 1][1][0];
      const unsigned short* pfa = nullptr;
      const unsigned short* pfb = nullptr;
      int nend = -1;
      if (kt < 14)        { pfa = wat + (kt + 2) * 64; pfb = wbt + (kt + 2) * 64; nend = 8; }
      else if (have_next) { pfa = nat + (kt - 14) * 64; pfb = nbt + (kt - 14) * 64; nend = 8; }
      else if (kt == 14)  { nend = 0; }

      // --- reads A-mq0 + B-nq0, MFMA quadrant (0,0)
#pragma unroll
      for (int mf = 0; mf < 4; ++mf) {
        a[mf][0] = *(const bf16x8*)(Ab + abase + mf * 2048 + lp[0]);
        a[mf][1] = *(const bf16x8*)(Ab + abase + mf * 2048 + lp[1]);
      }
#pragma unroll
      for (int j = 0; j < 2; ++j) {
        b[0][j][0] = *(const bf16x8*)(Bb + bbase + j * 2048 + lp[0]);
        b[0][j][1] = *(const bf16x8*)(Bb + bbase + j * 2048 + lp[1]);
      }
      __builtin_amdgcn_s_setprio(1); quad(0, 0); __builtin_amdgcn_s_setprio(0);
      // --- reads B-nq1, MFMA quadrant (0,1)
#pragma unroll
      for (int j = 0; j < 2; ++j) {
        b[1][j][0] = *(const bf16x8*)(Bb + bbase + 4096 + j * 2048 + lp[0]);
        b[1][j][1] = *(const bf16x8*)(Bb + bbase + 4096 + j * 2048 + lp[1]);
      }
      __builtin_amdgcn_s_setprio(1); quad(0, 1); __builtin_amdgcn_s_setprio(0);
      __builtin_amdgcn_s_barrier();            // all waves' B reads complete
      if (pfb) stage(pfb, Bb);                 // overwrite B region (safe)
      // --- reads A-mq1, MFMA quadrant (4,1)
#pragma unroll
      for (int mf = 0; mf < 4; ++mf) {
        a[mf][0] = *(const bf16x8*)(Ab + abase + 8192 + mf * 2048 + lp[0]);
        a[mf][1] = *(const bf16x8*)(Ab + abase + 8192 + mf * 2048 + lp[1]);
      }
      __builtin_amdgcn_s_setprio(1); quad(4, 1); __builtin_amdgcn_s_setprio(0);
      __builtin_amdgcn_s_barrier();            // all waves' A reads complete
      if (pfa) stage(pfa, Ab);                 // overwrite A region (safe)
      __builtin_amdgcn_sched_barrier(0);       // staging issues before MFMA cluster
      __builtin_amdgcn_s_setprio(1); quad(4, 0); __builtin_amdgcn_s_setprio(0);
      if (nend == 8)      asm volatile("s_waitcnt vmcnt(8)" ::: "memory");
      else if (nend == 0) asm volatile("s_waitcnt vmcnt(0)" ::: "memory");
      __builtin_amdgcn_s_barrier();
    }

    // Epilogue: pure stores (bias already in acc). C/D layout: col=lane&15,
    // row=(lane>>4)*4+j. nf innermost -> 4 consecutive 64B stores = 256B/row.
    const long long orow0 = off + (long long)tm * 256 + wm * 128;
#pragma unroll
    for (int am = 0; am < 8; ++am) {
      const int rl = (am >> 2) * 64 + (am & 3) * 16 + hi * 4;
#pragma unroll
      for (int j = 0; j < 4; ++j) {
        float* rp = out + (orow0 + rl + j) * (long long)DOUT_ + ocol0 + rsel;
        rp[0]  = acc[am][0][j];
        rp[16] = acc[am][1][j];
        rp[32] = acc[am][2][j];
        rp[48] = acc[am][3][j];
      }
    }
    wat = nat; wbt = nbt; tm = ntm; tn = ntn;
  }
}

// ---------------------------------------------------------------------------
// Fallback (ws too small): 128x128, reg-staged f32->bf16 (round-1 proven).
// ---------------------------------------------------------------------------
__global__ __launch_bounds__(256) void gemm_fb_kernel(const float* __restrict__ Af,
                                                      const float* __restrict__ Bf,
                                                      const float* __restrict__ bias,
                                                      const void* __restrict__ counts,
                                                      float* __restrict__ out) {
  constexpr int RS = 144;
  constexpr int BBASE = 128 * RS;
  __shared__ __align__(16) unsigned char lds[2 * 128 * RS];

  const int tid  = threadIdx.x;
  const int lane = tid & 63;
  const int wid  = tid >> 6;
  const int wm = wid >> 1, wn = wid & 1;

  const int bid = blockIdx.x;
  const int e  = bid >> 10;
  const int t  = bid & 1023;
  const int tm = t >> 5, tn = t & 31;

  const long long off = expert_offset(counts, e);
  const long long rowA0 = off + (long long)tm * 128;
  const int n0 = tn * 128;

  f32x4 acc[4][4] = {};

  for (int kt = 0; kt < DIN_ / 64; ++kt) {
    const int k0 = kt * 64;
#pragma unroll
    for (int rd = 0; rd < 8; ++rd) {
      const int chunk = rd * 256 + tid;
      const int c2 = chunk & 1023;
      const int r  = c2 >> 3;
      const int c  = c2 & 7;
      const float* src =
          (rd < 4) ? (Af + (rowA0 + r) * (long long)DIN_ + (k0 + c * 8))
                   : (Bf + ((long long)(e * DOUT_ + n0 + r)) * DIN_ + (k0 + c * 8));
      const float4 f0 = *reinterpret_cast<const float4*>(src);
      const float4 f1 = *reinterpret_cast<const float4*>(src + 4);
      s16x8 v;
      v[0] = (short)f2bf(f0.x); v[1] = (short)f2bf(f0.y);
      v[2] = (short)f2bf(f0.z); v[3] = (short)f2bf(f0.w);
      v[4] = (short)f2bf(f1.x); v[5] = (short)f2bf(f1.y);
      v[6] = (short)f2bf(f1.z); v[7] = (short)f2bf(f1.w);
      *reinterpret_cast<s16x8*>(&lds[((rd < 4) ? 0 : BBASE) + r * RS + (c << 4)]) = v;
    }
    __syncthreads();
#pragma unroll
    for (int kk = 0; kk < 2; ++kk) {
      const int rs = lane & 15;
      const int cs = kk * 4 + (lane >> 4);
      bf16x8 af[4], bfr[4];
#pragma unroll
      for (int mf = 0; mf < 4; ++mf)
        af[mf] = *reinterpret_cast<const bf16x8*>(&lds[(wm * 64 + mf * 16 + rs) * RS + (cs << 4)]);
#pragma unroll
      for (int nf = 0; nf < 4; ++nf)
        bfr[nf] = *reinterpret_cast<const bf16x8*>(&lds[BBASE + (wn * 64 + nf * 16 + rs) * RS + (cs << 4)]);
#pragma unroll
      for (int mf = 0; mf < 4; ++mf)
#pragma unroll
        for (int nf = 0; nf < 4; ++nf)
          acc[mf][nf] = __builtin_amdgcn_mfma_f32_16x16x32_bf16(af[mf], bfr[nf], acc[mf][nf], 0, 0, 0);
    }
    __syncthreads();
  }

  const long long orow0 = off + (long long)tm * 128 + wm * 64;
  const int ocol0 = n0 + wn * 64;
  const int rlo = (lane >> 4) * 4;
  const int c15 = lane & 15;
#pragma unroll
  for (int nf = 0; nf < 4; ++nf) {
    const int n = ocol0 + nf * 16 + c15;
    const float bv = bias[e * DOUT_ + n];
#pragma unroll
    for (int mf = 0; mf < 4; ++mf) {
      const long long mrow = orow0 + mf * 16 + rlo;
#pragma unroll
      for (int j = 0; j < 4; ++j)
        out[(mrow + j) * (long long)DOUT_ + n] = acc[mf][nf][j] + bv;
    }
  }
}

extern "C" void kernel_launch(void* const* d_in, const int* in_sizes, int n_in,
                              void* d_out, int out_size, void* d_ws, size_t ws_size,
                              hipStream_t stream) {
  const float* input  = (const float*)d_in[0];
  const float* weight = (const float*)d_in[1];
  const float* bias   = (const float*)d_in[2];
  const void*  counts = (const void*)d_in[3];
  float* out = (float*)d_out;

  const size_t nA = (size_t)T_ * DIN_;
  const size_t nW = (size_t)E_ * DOUT_ * DIN_;
  const size_t need = (nA + nW) * sizeof(unsigned short);

  if (ws_size >= need) {
    unsigned short* wa = (unsigned short*)d_ws;
    unsigned short* wb = wa + nA;
    const int nA4 = (int)(nA / 4), nW4 = (int)(nW / 4);
    cvt2_kernel<<<dim3((unsigned)((nA4 + nW4) / 256)), dim3(256), 0, stream>>>(
        input, weight, wa, wb, nA4, nW4);
    gemm4_kernel<<<dim3(256), dim3(512), 0, stream>>>(wa, wb, bias, counts, out);
  } else {
    gemm_fb_kernel<<<dim3(E_ * 32 * 32), dim3(256), 0, stream>>>(input, weight, bias, counts, out);
  }
}